// Round 7
// baseline (471.198 us; speedup 1.0000x reference)
//
#include <hip/hip_runtime.h>
#include <hip/hip_bf16.h>

#define D_FEAT 32
#define BUCKET_SHIFT 7
#define BUCKET_NODES 128           // 1 << BUCKET_SHIFT
#define MAX_NB 1024                // max buckets (single-block scan)
#define REC_CHUNK 4096             // records staged in LDS per chunk

typedef __attribute__((ext_vector_type(8))) unsigned short u16x8;
typedef __attribute__((ext_vector_type(8))) float f32x8;

// round-to-nearest-even f32 -> bf16 bits
static __device__ __forceinline__ unsigned short f2bf(float x) {
    unsigned int u = __float_as_uint(x);
    u += 0x7FFFu + ((u >> 16) & 1u);
    return (unsigned short)(u >> 16);
}
static __device__ __forceinline__ float bf2f(unsigned short b) {
    return __uint_as_float((unsigned int)b << 16);
}

// ---------------------------------------------------------------------------
// K0: per-node inverse L2 norm + bf16-compressed raw feature row (one 64B
// line per row). 8 lanes/node.
// ---------------------------------------------------------------------------
__global__ void prep_kernel(const float* __restrict__ feat,
                            unsigned short* __restrict__ nfb,
                            float* __restrict__ inv_norm, int n_nodes) {
    int g = blockIdx.x * blockDim.x + threadIdx.x;
    int node = g >> 3;
    int lane = g & 7;
    if (node >= n_nodes) return;
    float4 v = reinterpret_cast<const float4*>(feat + (size_t)node * D_FEAT)[lane];
    float ss = v.x * v.x + v.y * v.y + v.z * v.z + v.w * v.w;
    #pragma unroll
    for (int m = 4; m; m >>= 1) ss += __shfl_xor(ss, m, 8);
    if (lane == 0) inv_norm[node] = 1.0f / fmaxf(sqrtf(ss), 1e-12f);
    ushort4 b;
    b.x = f2bf(v.x); b.y = f2bf(v.y); b.z = f2bf(v.z); b.w = f2bf(v.w);
    reinterpret_cast<ushort4*>(nfb + (size_t)node * D_FEAT)[lane] = b;
}

// ---------------------------------------------------------------------------
// B1: bucket histogram (LDS-privatized; ~nb atomics per block, not per edge).
// ---------------------------------------------------------------------------
__global__ void bucket_hist_kernel(const int* __restrict__ dst,
                                   int* __restrict__ bucket_cnt,
                                   int n_edges, int nb) {
    __shared__ int h[MAX_NB];
    for (int i = threadIdx.x; i < nb; i += blockDim.x) h[i] = 0;
    __syncthreads();
    int stride = gridDim.x * blockDim.x;
    for (int e = blockIdx.x * blockDim.x + threadIdx.x; e < n_edges; e += stride)
        atomicAdd(&h[dst[e] >> BUCKET_SHIFT], 1);
    __syncthreads();
    for (int i = threadIdx.x; i < nb; i += blockDim.x)
        if (h[i]) atomicAdd(&bucket_cnt[i], h[i]);
}

// ---------------------------------------------------------------------------
// B2: single-block exclusive scan of bucket counts -> base + cursor.
// ---------------------------------------------------------------------------
__global__ void bucket_scan_kernel(const int* __restrict__ bucket_cnt,
                                   int* __restrict__ bucket_base,
                                   int* __restrict__ bucket_cursor,
                                   int nb, int n_edges) {
    __shared__ int tmp[MAX_NB];
    int t = threadIdx.x;
    int v = (t < nb) ? bucket_cnt[t] : 0;
    tmp[t] = v;
    __syncthreads();
    for (int off = 1; off < MAX_NB; off <<= 1) {
        int add = (t >= off) ? tmp[t - off] : 0;
        __syncthreads();
        tmp[t] += add;
        __syncthreads();
    }
    if (t < nb) {
        int ex = tmp[t] - v;
        bucket_base[t] = ex;
        bucket_cursor[t] = ex;
    }
    if (t == 0) bucket_base[nb] = n_edges;
}

// ---------------------------------------------------------------------------
// B3: scatter packed records (src<<7 | dst_low) into bucket regions.
// atomicAdd on 782 HOT counters (pipelines well); record store is
// non-temporal so partial lines merge at the shared memory-side cache
// instead of ping-ponging across per-XCD L2s.
// ---------------------------------------------------------------------------
__global__ void bucket_scatter_kernel(const int* __restrict__ src,
                                      const int* __restrict__ dst,
                                      int* __restrict__ bucket_cursor,
                                      int* __restrict__ recs, int n_edges) {
    int e = blockIdx.x * blockDim.x + threadIdx.x;
    if (e >= n_edges) return;
    int d = dst[e];
    int s = src[e];
    int pos = atomicAdd(&bucket_cursor[d >> BUCKET_SHIFT], 1);
    __builtin_nontemporal_store((s << BUCKET_SHIFT) | (d & (BUCKET_NODES - 1)),
                                &recs[pos]);
}

// ---------------------------------------------------------------------------
// C: per-bucket aggregation. One block per bucket (256 thr = 32 groups x 8).
// Per REC_CHUNK: LDS counting-sort records by dst_low, then each group
// register-accumulates its 4 owned nodes' contiguous runs (bf16 gather of
// feat[src] rows, dot vs cached bn, exp, weighted sum). Single coalesced
// row write per node. No global atomics, no chains.
// ---------------------------------------------------------------------------
__global__ __launch_bounds__(256) void bucket_aggregate_kernel(
    const unsigned short* __restrict__ nfb,
    const float* __restrict__ inv_norm,
    const int* __restrict__ bucket_base,
    const int* __restrict__ recs,
    const float* __restrict__ beta,
    float* __restrict__ out, int n_nodes) {

    __shared__ int s_rec[REC_CHUNK];
    __shared__ int s_hist[BUCKET_NODES];
    __shared__ int s_off[BUCKET_NODES];

    int b = blockIdx.x;
    int node0 = b * BUCKET_NODES;
    int start = bucket_base[b];
    int end   = bucket_base[b + 1];
    int t = threadIdx.x;
    int group = t >> 3;   // 0..31
    int lane  = t & 7;
    float bscale = beta[0];

    // load bn rows (normalized) for the 4 owned nodes of this group
    float4 bn[4];
    float4 acc[4];
    float  ssum[4];
    #pragma unroll
    for (int r = 0; r < 4; ++r) {
        int v = node0 + r * 32 + group;
        acc[r] = make_float4(0.f, 0.f, 0.f, 0.f);
        ssum[r] = 0.f;
        bn[r] = make_float4(0.f, 0.f, 0.f, 0.f);
        if (v < n_nodes) {
            ushort4 braw = reinterpret_cast<const ushort4*>(nfb + (size_t)v * D_FEAT)[lane];
            float invv = inv_norm[v];
            bn[r].x = bf2f(braw.x) * invv;
            bn[r].y = bf2f(braw.y) * invv;
            bn[r].z = bf2f(braw.z) * invv;
            bn[r].w = bf2f(braw.w) * invv;
        }
    }

    for (int cbase = start; cbase < end; cbase += REC_CHUNK) {
        int cnt = min(REC_CHUNK, end - cbase);

        if (t < BUCKET_NODES) s_hist[t] = 0;
        __syncthreads();
        for (int i = t; i < cnt; i += 256)
            atomicAdd(&s_hist[recs[cbase + i] & (BUCKET_NODES - 1)], 1);
        __syncthreads();

        // inclusive scan of hist into s_off
        if (t < BUCKET_NODES) s_off[t] = s_hist[t];
        __syncthreads();
        for (int off = 1; off < BUCKET_NODES; off <<= 1) {
            int add = (t >= off && t < BUCKET_NODES) ? s_off[t - off] : 0;
            __syncthreads();
            if (t < BUCKET_NODES) s_off[t] += add;
            __syncthreads();
        }
        // s_hist := run start cursor
        if (t < BUCKET_NODES) s_hist[t] = s_off[t] - s_hist[t];
        __syncthreads();
        for (int i = t; i < cnt; i += 256) {
            int r = recs[cbase + i];
            int pos = atomicAdd(&s_hist[r & (BUCKET_NODES - 1)], 1);
            s_rec[pos] = r;
        }
        __syncthreads();

        // consume runs: group handles dl = r*32 + group
        #pragma unroll
        for (int r = 0; r < 4; ++r) {
            int dl = r * 32 + group;
            int rs = dl ? s_off[dl - 1] : 0;
            int re = s_off[dl];
            for (int i = rs; i < re; ++i) {
                int rec = s_rec[i];                 // uniform in group: broadcast
                int u = ((unsigned)rec) >> BUCKET_SHIFT;
                float invu = inv_norm[u];
                ushort4 araw = reinterpret_cast<const ushort4*>(nfb + (size_t)u * D_FEAT)[lane];
                float4 a;
                a.x = bf2f(araw.x); a.y = bf2f(araw.y);
                a.z = bf2f(araw.z); a.w = bf2f(araw.w);
                float d = a.x * bn[r].x;
                d = fmaf(a.y, bn[r].y, d);
                d = fmaf(a.z, bn[r].z, d);
                d = fmaf(a.w, bn[r].w, d);
                d += __shfl_xor(d, 1, 8);
                d += __shfl_xor(d, 2, 8);
                d += __shfl_xor(d, 4, 8);
                float pe = __expf(bscale * d * invu);  // |arg|<=beta: no max-shift
                acc[r].x = fmaf(pe, a.x, acc[r].x);
                acc[r].y = fmaf(pe, a.y, acc[r].y);
                acc[r].z = fmaf(pe, a.z, acc[r].z);
                acc[r].w = fmaf(pe, a.w, acc[r].w);
                ssum[r] += pe;
            }
        }
        __syncthreads();
    }

    // write rows (coalesced: consecutive groups -> consecutive nodes)
    #pragma unroll
    for (int r = 0; r < 4; ++r) {
        int v = node0 + r * 32 + group;
        if (v < n_nodes) {
            float inv_s = (ssum[r] > 0.f) ? (1.0f / ssum[r]) : 0.0f;
            float4 o = make_float4(acc[r].x * inv_s, acc[r].y * inv_s,
                                   acc[r].z * inv_s, acc[r].w * inv_s);
            reinterpret_cast<float4*>(out + (size_t)v * D_FEAT)[lane] = o;
        }
    }
}

// ---------------------------------------------------------------------------
// Fallback 1 (R6): packed linked-list + bf16 chase.
// ---------------------------------------------------------------------------
__global__ void link_packed_kernel(const int* __restrict__ src,
                                   const int* __restrict__ dst,
                                   int* __restrict__ head,
                                   int2* __restrict__ rec, int n_edges) {
    int stride = gridDim.x * blockDim.x;
    for (int e = blockIdx.x * blockDim.x + threadIdx.x; e < n_edges; e += stride) {
        int d = dst[e];
        int s = src[e];
        int old = atomicExch(&head[d], e);
        rec[e] = make_int2(old, s);
    }
}

__global__ void fused_chase_bf16_kernel(const unsigned short* __restrict__ nfb,
                                        const float* __restrict__ inv_norm,
                                        const int* __restrict__ head,
                                        const int2* __restrict__ rec,
                                        const float* __restrict__ beta,
                                        float* __restrict__ out, int n_nodes) {
    int g = blockIdx.x * blockDim.x + threadIdx.x;
    int node = g >> 2;
    int lane = g & 3;
    if (node >= n_nodes) return;

    float bscale = beta[0];
    float invv = inv_norm[node];
    u16x8 braw = reinterpret_cast<const u16x8*>(nfb + (size_t)node * D_FEAT)[lane];
    f32x8 bn;
    #pragma unroll
    for (int j = 0; j < 8; ++j) bn[j] = bf2f(braw[j]) * invv;

    f32x8 acc;
    #pragma unroll
    for (int j = 0; j < 8; ++j) acc[j] = 0.f;
    float ssum = 0.f;

    int e = head[node];
    while (e >= 0) {
        int2 r = rec[e];
        int en = r.x, u = r.y;
        float invu = inv_norm[u];
        u16x8 araw = reinterpret_cast<const u16x8*>(nfb + (size_t)u * D_FEAT)[lane];
        f32x8 a;
        float d = 0.f;
        #pragma unroll
        for (int j = 0; j < 8; ++j) {
            a[j] = bf2f(araw[j]);
            d = fmaf(a[j], bn[j], d);
        }
        d += __shfl_xor(d, 1, 4);
        d += __shfl_xor(d, 2, 4);
        float pe = __expf(bscale * d * invu);
        #pragma unroll
        for (int j = 0; j < 8; ++j) acc[j] = fmaf(pe, a[j], acc[j]);
        ssum += pe;
        e = en;
    }

    float inv_s = (ssum > 0.f) ? (1.0f / ssum) : 0.0f;
    float* op = out + (size_t)node * D_FEAT + lane * 8;
    reinterpret_cast<float4*>(op)[0] =
        make_float4(acc[0] * inv_s, acc[1] * inv_s, acc[2] * inv_s, acc[3] * inv_s);
    reinterpret_cast<float4*>(op)[1] =
        make_float4(acc[4] * inv_s, acc[5] * inv_s, acc[6] * inv_s, acc[7] * inv_s);
}

// ---------------------------------------------------------------------------
// Fallback 2 (tiny ws): f32 atomic path.
// ---------------------------------------------------------------------------
__global__ void node_invnorm_kernel(const float* __restrict__ feat,
                                    float* __restrict__ inv_norm, int n_nodes) {
    int g = blockIdx.x * blockDim.x + threadIdx.x;
    int node = g >> 3;
    int lane = g & 7;
    if (node >= n_nodes) return;
    float4 v = reinterpret_cast<const float4*>(feat + (size_t)node * D_FEAT)[lane];
    float ss = v.x * v.x + v.y * v.y + v.z * v.z + v.w * v.w;
    #pragma unroll
    for (int m = 4; m; m >>= 1) ss += __shfl_xor(ss, m, 8);
    if (lane == 0) inv_norm[node] = 1.0f / fmaxf(sqrtf(ss), 1e-12f);
}

__global__ void edge_p_kernel(const float* __restrict__ feat,
                              const float* __restrict__ inv_norm,
                              const int* __restrict__ src,
                              const int* __restrict__ dst,
                              const float* __restrict__ beta,
                              float* __restrict__ p, float* __restrict__ s,
                              int n_edges) {
    int g = blockIdx.x * blockDim.x + threadIdx.x;
    int e = g >> 3;
    int lane = g & 7;
    if (e >= n_edges) return;
    int u = src[e];
    int v = dst[e];
    float4 a = reinterpret_cast<const float4*>(feat + (size_t)u * D_FEAT)[lane];
    float4 b = reinterpret_cast<const float4*>(feat + (size_t)v * D_FEAT)[lane];
    float d = a.x * b.x;
    d = fmaf(a.y, b.y, d);
    d = fmaf(a.z, b.z, d);
    d = fmaf(a.w, b.w, d);
    #pragma unroll
    for (int m = 4; m; m >>= 1) d += __shfl_xor(d, m, 8);
    if (lane == 0) {
        float pe = __expf(beta[0] * d * inv_norm[u] * inv_norm[v]);
        p[e] = pe;
        atomicAdd(&s[v], pe);
    }
}

__global__ void aggregate_atomic_kernel(const float* __restrict__ feat,
                                        const int* __restrict__ src,
                                        const int* __restrict__ dst,
                                        const float* __restrict__ p,
                                        const float* __restrict__ s,
                                        float* __restrict__ out, int n_edges) {
    int g = blockIdx.x * blockDim.x + threadIdx.x;
    int e = g >> 5;
    int lane = g & 31;
    if (e >= n_edges) return;
    int u = src[e];
    int v = dst[e];
    float w = p[e] / s[v];
    atomicAdd(&out[(size_t)v * D_FEAT + lane], feat[(size_t)u * D_FEAT + lane] * w);
}

extern "C" void kernel_launch(void* const* d_in, const int* in_sizes, int n_in,
                              void* d_out, int out_size, void* d_ws, size_t ws_size,
                              hipStream_t stream) {
    const float* feat = (const float*)d_in[0];
    const float* beta = (const float*)d_in[1];
    const int*   src  = (const int*)d_in[2];
    const int*   dst  = (const int*)d_in[3];
    float* out = (float*)d_out;

    int n_nodes = in_sizes[0] / D_FEAT;
    int n_edges = in_sizes[2];
    int nb = (n_nodes + BUCKET_NODES - 1) / BUCKET_NODES;

    // bucket-path ws (bytes): nfb[N*32*2] | inv_norm[N] | bucket_cnt[MAX_NB]
    //   | bucket_base[MAX_NB+1] | bucket_cursor[MAX_NB] | recs[E]
    size_t nfb_bytes = (size_t)n_nodes * D_FEAT * 2;
    size_t need_bucket = nfb_bytes + (size_t)n_nodes * 4 +
                         (size_t)(3 * MAX_NB + 1) * 4 + (size_t)n_edges * 4;
    size_t need_ll = nfb_bytes + (size_t)n_nodes * 8 + (size_t)n_edges * 8;

    bool bucket_ok = (ws_size >= need_bucket) && (nb <= MAX_NB) &&
                     (n_nodes <= (1 << 24));

    if (bucket_ok) {
        unsigned short* nfb = (unsigned short*)d_ws;
        float* inv_norm     = (float*)((char*)d_ws + nfb_bytes);
        int* bucket_cnt     = (int*)(inv_norm + n_nodes);
        int* bucket_base    = bucket_cnt + MAX_NB;
        int* bucket_cursor  = bucket_base + (MAX_NB + 1);
        int* recs           = bucket_cursor + MAX_NB;

        hipMemsetAsync(bucket_cnt, 0, MAX_NB * sizeof(int), stream);

        {
            int total = n_nodes * 8;
            prep_kernel<<<(total + 255) / 256, 256, 0, stream>>>(
                feat, nfb, inv_norm, n_nodes);
        }
        bucket_hist_kernel<<<512, 256, 0, stream>>>(dst, bucket_cnt, n_edges, nb);
        bucket_scan_kernel<<<1, MAX_NB, 0, stream>>>(
            bucket_cnt, bucket_base, bucket_cursor, nb, n_edges);
        bucket_scatter_kernel<<<(n_edges + 255) / 256, 256, 0, stream>>>(
            src, dst, bucket_cursor, recs, n_edges);
        bucket_aggregate_kernel<<<nb, 256, 0, stream>>>(
            nfb, inv_norm, bucket_base, recs, beta, out, n_nodes);
    } else if (ws_size >= need_ll) {
        unsigned short* nfb = (unsigned short*)d_ws;
        float* inv_norm = (float*)((char*)d_ws + nfb_bytes);
        int*   head     = (int*)(inv_norm + n_nodes);
        int2*  rec      = (int2*)(head + n_nodes);

        hipMemsetAsync(head, 0xFF, (size_t)n_nodes * sizeof(int), stream);
        {
            int total = n_nodes * 8;
            prep_kernel<<<(total + 255) / 256, 256, 0, stream>>>(
                feat, nfb, inv_norm, n_nodes);
        }
        link_packed_kernel<<<2048, 256, 0, stream>>>(src, dst, head, rec, n_edges);
        {
            int total = n_nodes * 4;
            fused_chase_bf16_kernel<<<(total + 255) / 256, 256, 0, stream>>>(
                nfb, inv_norm, head, rec, beta, out, n_nodes);
        }
    } else {
        float* inv_norm = (float*)d_ws;
        float* s_sum    = inv_norm + n_nodes;
        float* p        = s_sum + n_nodes;

        hipMemsetAsync(s_sum, 0, (size_t)n_nodes * sizeof(float), stream);
        hipMemsetAsync(out, 0, (size_t)out_size * sizeof(float), stream);

        {
            int total = n_nodes * 8;
            node_invnorm_kernel<<<(total + 255) / 256, 256, 0, stream>>>(
                feat, inv_norm, n_nodes);
        }
        {
            long long total = (long long)n_edges * 8;
            edge_p_kernel<<<(int)((total + 255) / 256), 256, 0, stream>>>(
                feat, inv_norm, src, dst, beta, p, s_sum, n_edges);
        }
        {
            long long total = (long long)n_edges * 32;
            aggregate_atomic_kernel<<<(int)((total + 255) / 256), 256, 0, stream>>>(
                feat, src, dst, p, s_sum, out, n_edges);
        }
    }
}

// Round 8
// 201.765 us; speedup vs baseline: 2.3354x; 2.3354x over previous
//
#include <hip/hip_runtime.h>
#include <hip/hip_bf16.h>

#define D_FEAT 32
#define BUCKET_SHIFT 7
#define BUCKET_NODES 128           // 1 << BUCKET_SHIFT
#define MAX_NB 1024                // max buckets
#define CHUNK_E 8192               // edges per sort chunk
#define REC_CHUNK 4096             // records staged in LDS per aggregate chunk

typedef __attribute__((ext_vector_type(8))) unsigned short u16x8;
typedef __attribute__((ext_vector_type(8))) float f32x8;

// round-to-nearest-even f32 -> bf16 bits
static __device__ __forceinline__ unsigned short f2bf(float x) {
    unsigned int u = __float_as_uint(x);
    u += 0x7FFFu + ((u >> 16) & 1u);
    return (unsigned short)(u >> 16);
}
static __device__ __forceinline__ float bf2f(unsigned short b) {
    return __uint_as_float((unsigned int)b << 16);
}

// ---------------------------------------------------------------------------
// K0: per-node inverse L2 norm + bf16-compressed raw feature row (one 64B
// line per row). 8 lanes/node.
// ---------------------------------------------------------------------------
__global__ void prep_kernel(const float* __restrict__ feat,
                            unsigned short* __restrict__ nfb,
                            float* __restrict__ inv_norm, int n_nodes) {
    int g = blockIdx.x * blockDim.x + threadIdx.x;
    int node = g >> 3;
    int lane = g & 7;
    if (node >= n_nodes) return;
    float4 v = reinterpret_cast<const float4*>(feat + (size_t)node * D_FEAT)[lane];
    float ss = v.x * v.x + v.y * v.y + v.z * v.z + v.w * v.w;
    #pragma unroll
    for (int m = 4; m; m >>= 1) ss += __shfl_xor(ss, m, 8);
    if (lane == 0) inv_norm[node] = 1.0f / fmaxf(sqrtf(ss), 1e-12f);
    ushort4 b;
    b.x = f2bf(v.x); b.y = f2bf(v.y); b.z = f2bf(v.z); b.w = f2bf(v.w);
    reinterpret_cast<ushort4*>(nfb + (size_t)node * D_FEAT)[lane] = b;
}

// ---------------------------------------------------------------------------
// S1: per-chunk bucket histogram (LDS only; NO global atomics).
// chunk_hist is TRANSPOSED: chunk_hist[b * nchunk + c].
// ---------------------------------------------------------------------------
__global__ __launch_bounds__(256) void hist_kernel(const int* __restrict__ dst,
                                                   int* __restrict__ chunk_hist,
                                                   int n_edges, int nb, int nchunk) {
    __shared__ int s_h[MAX_NB];
    int c = blockIdx.x;
    int t = threadIdx.x;
    for (int i = t; i < MAX_NB; i += 256) s_h[i] = 0;
    __syncthreads();
    int base = c * CHUNK_E;
    int cnt = min(CHUNK_E, n_edges - base);
    for (int k = t; k < cnt; k += 256)
        atomicAdd(&s_h[dst[base + k] >> BUCKET_SHIFT], 1);
    __syncthreads();
    for (int i = t; i < nb; i += 256)
        chunk_hist[(size_t)i * nchunk + c] = s_h[i];
}

// ---------------------------------------------------------------------------
// S2: per-bucket serial prefix over chunks (rows are contiguous after the
// transpose -> fully pipelined dword loads). In-place: chunk_hist becomes
// the within-bucket offset of each chunk; total[b] = bucket size.
// ---------------------------------------------------------------------------
__global__ void col_prefix_kernel(int* __restrict__ chunk_hist,
                                  int* __restrict__ total, int nchunk, int nb) {
    int b = blockIdx.x * blockDim.x + threadIdx.x;
    if (b >= nb) return;
    int* row = chunk_hist + (size_t)b * nchunk;
    int run = 0;
    for (int c = 0; c < nchunk; ++c) {
        int v = row[c];
        row[c] = run;
        run += v;
    }
    total[b] = run;
}

// ---------------------------------------------------------------------------
// S3: single-block exclusive scan of bucket totals -> bucket_base.
// ---------------------------------------------------------------------------
__global__ __launch_bounds__(256) void base_scan_kernel(const int* __restrict__ total,
                                                        int* __restrict__ bucket_base,
                                                        int nb, int n_edges) {
    __shared__ int s_sum[256];
    int t = threadIdx.x;
    int i0 = t * 4;
    int a0 = (i0 + 0 < nb) ? total[i0 + 0] : 0;
    int a1 = (i0 + 1 < nb) ? total[i0 + 1] : 0;
    int a2 = (i0 + 2 < nb) ? total[i0 + 2] : 0;
    int a3 = (i0 + 3 < nb) ? total[i0 + 3] : 0;
    int tsum = a0 + a1 + a2 + a3;
    s_sum[t] = tsum;
    __syncthreads();
    for (int off = 1; off < 256; off <<= 1) {
        int add = (t >= off) ? s_sum[t - off] : 0;
        __syncthreads();
        s_sum[t] += add;
        __syncthreads();
    }
    int excl = s_sum[t] - tsum;
    if (i0 + 0 < nb) bucket_base[i0 + 0] = excl;
    if (i0 + 1 < nb) bucket_base[i0 + 1] = excl + a0;
    if (i0 + 2 < nb) bucket_base[i0 + 2] = excl + a0 + a1;
    if (i0 + 3 < nb) bucket_base[i0 + 3] = excl + a0 + a1 + a2;
    if (t == 0) bucket_base[nb] = n_edges;
}

// ---------------------------------------------------------------------------
// S4: scatter. Per chunk: LDS counting sort of 8192 records by bucket, then
// copy each bucket-run to its PRECOMPUTED global slot. Zero global atomics;
// runs (~10 recs avg) are contiguous stores.
// ---------------------------------------------------------------------------
__global__ __launch_bounds__(256) void scatter_kernel(const int* __restrict__ src,
                                                      const int* __restrict__ dst,
                                                      const int* __restrict__ chunk_hist,
                                                      const int* __restrict__ bucket_base,
                                                      int* __restrict__ recs,
                                                      int n_edges, int nb, int nchunk) {
    __shared__ int s_cur[MAX_NB];       // hist, then run cursor
    __shared__ int s_off[MAX_NB + 1];   // exclusive offsets (+ sentinel)
    __shared__ int s_gbase[MAX_NB];     // global base of this chunk's run
    __shared__ int s_sum[256];
    __shared__ int s_rec[CHUNK_E];

    int c = blockIdx.x;
    int t = threadIdx.x;
    int base = c * CHUNK_E;
    int cnt = min(CHUNK_E, n_edges - base);

    for (int i = t; i < MAX_NB; i += 256) s_cur[i] = 0;
    __syncthreads();
    for (int k = t; k < cnt; k += 256)
        atomicAdd(&s_cur[dst[base + k] >> BUCKET_SHIFT], 1);
    __syncthreads();

    // exclusive scan of s_cur[1024] -> s_off (4 items/thread)
    int i0 = t * 4;
    int a0 = s_cur[i0], a1 = s_cur[i0 + 1], a2 = s_cur[i0 + 2], a3 = s_cur[i0 + 3];
    int tsum = a0 + a1 + a2 + a3;
    s_sum[t] = tsum;
    __syncthreads();
    for (int off = 1; off < 256; off <<= 1) {
        int add = (t >= off) ? s_sum[t - off] : 0;
        __syncthreads();
        s_sum[t] += add;
        __syncthreads();
    }
    int excl = s_sum[t] - tsum;
    s_off[i0 + 0] = excl;
    s_off[i0 + 1] = excl + a0;
    s_off[i0 + 2] = excl + a0 + a1;
    s_off[i0 + 3] = excl + a0 + a1 + a2;
    if (t == 255) s_off[MAX_NB] = excl + tsum;  // == cnt
    __syncthreads();
    // cursors := offsets; stage global run bases (bucket_base + chunk offset)
    for (int i = t; i < MAX_NB; i += 256) s_cur[i] = s_off[i];
    for (int i = t; i < nb; i += 256)
        s_gbase[i] = bucket_base[i] + chunk_hist[(size_t)i * nchunk + c];
    __syncthreads();

    // place records into LDS in bucket-sorted order
    for (int k = t; k < cnt; k += 256) {
        int d = dst[base + k];
        int s = src[base + k];
        int b = d >> BUCKET_SHIFT;
        int lpos = atomicAdd(&s_cur[b], 1);
        s_rec[lpos] = (s << BUCKET_SHIFT) | (d & (BUCKET_NODES - 1));
    }
    __syncthreads();

    // copy out: find run via binary search (max b with s_off[b] <= i)
    for (int i = t; i < cnt; i += 256) {
        int lo = 0, hi = MAX_NB;
        while (hi - lo > 1) {
            int mid = (lo + hi) >> 1;
            if (s_off[mid] <= i) lo = mid; else hi = mid;
        }
        recs[s_gbase[lo] + (i - s_off[lo])] = s_rec[i];
    }
}

// ---------------------------------------------------------------------------
// C: per-bucket aggregation (proven in R7). One block per bucket; LDS
// counting-sort by dst_low, then 8-lane groups register-accumulate their
// nodes' runs. Single coalesced row write per node; no global atomics.
// ---------------------------------------------------------------------------
__global__ __launch_bounds__(256) void bucket_aggregate_kernel(
    const unsigned short* __restrict__ nfb,
    const float* __restrict__ inv_norm,
    const int* __restrict__ bucket_base,
    const int* __restrict__ recs,
    const float* __restrict__ beta,
    float* __restrict__ out, int n_nodes) {

    __shared__ int s_rec[REC_CHUNK];
    __shared__ int s_hist[BUCKET_NODES];
    __shared__ int s_off[BUCKET_NODES];

    int b = blockIdx.x;
    int node0 = b * BUCKET_NODES;
    int start = bucket_base[b];
    int end   = bucket_base[b + 1];
    int t = threadIdx.x;
    int group = t >> 3;   // 0..31
    int lane  = t & 7;
    float bscale = beta[0];

    float4 bn[4];
    float4 acc[4];
    float  ssum[4];
    #pragma unroll
    for (int r = 0; r < 4; ++r) {
        int v = node0 + r * 32 + group;
        acc[r] = make_float4(0.f, 0.f, 0.f, 0.f);
        ssum[r] = 0.f;
        bn[r] = make_float4(0.f, 0.f, 0.f, 0.f);
        if (v < n_nodes) {
            ushort4 braw = reinterpret_cast<const ushort4*>(nfb + (size_t)v * D_FEAT)[lane];
            float invv = inv_norm[v];
            bn[r].x = bf2f(braw.x) * invv;
            bn[r].y = bf2f(braw.y) * invv;
            bn[r].z = bf2f(braw.z) * invv;
            bn[r].w = bf2f(braw.w) * invv;
        }
    }

    for (int cbase = start; cbase < end; cbase += REC_CHUNK) {
        int cnt = min(REC_CHUNK, end - cbase);

        if (t < BUCKET_NODES) s_hist[t] = 0;
        __syncthreads();
        for (int i = t; i < cnt; i += 256)
            atomicAdd(&s_hist[recs[cbase + i] & (BUCKET_NODES - 1)], 1);
        __syncthreads();

        if (t < BUCKET_NODES) s_off[t] = s_hist[t];
        __syncthreads();
        for (int off = 1; off < BUCKET_NODES; off <<= 1) {
            int add = (t >= off && t < BUCKET_NODES) ? s_off[t - off] : 0;
            __syncthreads();
            if (t < BUCKET_NODES) s_off[t] += add;
            __syncthreads();
        }
        if (t < BUCKET_NODES) s_hist[t] = s_off[t] - s_hist[t];  // run cursor
        __syncthreads();
        for (int i = t; i < cnt; i += 256) {
            int r = recs[cbase + i];
            int pos = atomicAdd(&s_hist[r & (BUCKET_NODES - 1)], 1);
            s_rec[pos] = r;
        }
        __syncthreads();

        #pragma unroll
        for (int r = 0; r < 4; ++r) {
            int dl = r * 32 + group;
            int rs = dl ? s_off[dl - 1] : 0;
            int re = s_off[dl];
            for (int i = rs; i < re; ++i) {
                int rec = s_rec[i];                 // uniform in group: broadcast
                int u = ((unsigned)rec) >> BUCKET_SHIFT;
                float invu = inv_norm[u];
                ushort4 araw = reinterpret_cast<const ushort4*>(nfb + (size_t)u * D_FEAT)[lane];
                float4 a;
                a.x = bf2f(araw.x); a.y = bf2f(araw.y);
                a.z = bf2f(araw.z); a.w = bf2f(araw.w);
                float d = a.x * bn[r].x;
                d = fmaf(a.y, bn[r].y, d);
                d = fmaf(a.z, bn[r].z, d);
                d = fmaf(a.w, bn[r].w, d);
                d += __shfl_xor(d, 1, 8);
                d += __shfl_xor(d, 2, 8);
                d += __shfl_xor(d, 4, 8);
                float pe = __expf(bscale * d * invu);  // |arg|<=beta: no max-shift
                acc[r].x = fmaf(pe, a.x, acc[r].x);
                acc[r].y = fmaf(pe, a.y, acc[r].y);
                acc[r].z = fmaf(pe, a.z, acc[r].z);
                acc[r].w = fmaf(pe, a.w, acc[r].w);
                ssum[r] += pe;
            }
        }
        __syncthreads();
    }

    #pragma unroll
    for (int r = 0; r < 4; ++r) {
        int v = node0 + r * 32 + group;
        if (v < n_nodes) {
            float inv_s = (ssum[r] > 0.f) ? (1.0f / ssum[r]) : 0.0f;
            float4 o = make_float4(acc[r].x * inv_s, acc[r].y * inv_s,
                                   acc[r].z * inv_s, acc[r].w * inv_s);
            reinterpret_cast<float4*>(out + (size_t)v * D_FEAT)[lane] = o;
        }
    }
}

// ---------------------------------------------------------------------------
// Fallback 1 (proven R6): packed linked-list + bf16 chase.
// ---------------------------------------------------------------------------
__global__ void link_packed_kernel(const int* __restrict__ src,
                                   const int* __restrict__ dst,
                                   int* __restrict__ head,
                                   int2* __restrict__ rec, int n_edges) {
    int stride = gridDim.x * blockDim.x;
    for (int e = blockIdx.x * blockDim.x + threadIdx.x; e < n_edges; e += stride) {
        int d = dst[e];
        int s = src[e];
        int old = atomicExch(&head[d], e);
        rec[e] = make_int2(old, s);
    }
}

__global__ void fused_chase_bf16_kernel(const unsigned short* __restrict__ nfb,
                                        const float* __restrict__ inv_norm,
                                        const int* __restrict__ head,
                                        const int2* __restrict__ rec,
                                        const float* __restrict__ beta,
                                        float* __restrict__ out, int n_nodes) {
    int g = blockIdx.x * blockDim.x + threadIdx.x;
    int node = g >> 2;
    int lane = g & 3;
    if (node >= n_nodes) return;

    float bscale = beta[0];
    float invv = inv_norm[node];
    u16x8 braw = reinterpret_cast<const u16x8*>(nfb + (size_t)node * D_FEAT)[lane];
    f32x8 bn;
    #pragma unroll
    for (int j = 0; j < 8; ++j) bn[j] = bf2f(braw[j]) * invv;

    f32x8 acc;
    #pragma unroll
    for (int j = 0; j < 8; ++j) acc[j] = 0.f;
    float ssum = 0.f;

    int e = head[node];
    while (e >= 0) {
        int2 r = rec[e];
        int en = r.x, u = r.y;
        float invu = inv_norm[u];
        u16x8 araw = reinterpret_cast<const u16x8*>(nfb + (size_t)u * D_FEAT)[lane];
        f32x8 a;
        float d = 0.f;
        #pragma unroll
        for (int j = 0; j < 8; ++j) {
            a[j] = bf2f(araw[j]);
            d = fmaf(a[j], bn[j], d);
        }
        d += __shfl_xor(d, 1, 4);
        d += __shfl_xor(d, 2, 4);
        float pe = __expf(bscale * d * invu);
        #pragma unroll
        for (int j = 0; j < 8; ++j) acc[j] = fmaf(pe, a[j], acc[j]);
        ssum += pe;
        e = en;
    }

    float inv_s = (ssum > 0.f) ? (1.0f / ssum) : 0.0f;
    float* op = out + (size_t)node * D_FEAT + lane * 8;
    reinterpret_cast<float4*>(op)[0] =
        make_float4(acc[0] * inv_s, acc[1] * inv_s, acc[2] * inv_s, acc[3] * inv_s);
    reinterpret_cast<float4*>(op)[1] =
        make_float4(acc[4] * inv_s, acc[5] * inv_s, acc[6] * inv_s, acc[7] * inv_s);
}

// ---------------------------------------------------------------------------
// Fallback 2 (tiny ws): f32 atomic path.
// ---------------------------------------------------------------------------
__global__ void node_invnorm_kernel(const float* __restrict__ feat,
                                    float* __restrict__ inv_norm, int n_nodes) {
    int g = blockIdx.x * blockDim.x + threadIdx.x;
    int node = g >> 3;
    int lane = g & 7;
    if (node >= n_nodes) return;
    float4 v = reinterpret_cast<const float4*>(feat + (size_t)node * D_FEAT)[lane];
    float ss = v.x * v.x + v.y * v.y + v.z * v.z + v.w * v.w;
    #pragma unroll
    for (int m = 4; m; m >>= 1) ss += __shfl_xor(ss, m, 8);
    if (lane == 0) inv_norm[node] = 1.0f / fmaxf(sqrtf(ss), 1e-12f);
}

__global__ void edge_p_kernel(const float* __restrict__ feat,
                              const float* __restrict__ inv_norm,
                              const int* __restrict__ src,
                              const int* __restrict__ dst,
                              const float* __restrict__ beta,
                              float* __restrict__ p, float* __restrict__ s,
                              int n_edges) {
    int g = blockIdx.x * blockDim.x + threadIdx.x;
    int e = g >> 3;
    int lane = g & 7;
    if (e >= n_edges) return;
    int u = src[e];
    int v = dst[e];
    float4 a = reinterpret_cast<const float4*>(feat + (size_t)u * D_FEAT)[lane];
    float4 b = reinterpret_cast<const float4*>(feat + (size_t)v * D_FEAT)[lane];
    float d = a.x * b.x;
    d = fmaf(a.y, b.y, d);
    d = fmaf(a.z, b.z, d);
    d = fmaf(a.w, b.w, d);
    #pragma unroll
    for (int m = 4; m; m >>= 1) d += __shfl_xor(d, m, 8);
    if (lane == 0) {
        float pe = __expf(beta[0] * d * inv_norm[u] * inv_norm[v]);
        p[e] = pe;
        atomicAdd(&s[v], pe);
    }
}

__global__ void aggregate_atomic_kernel(const float* __restrict__ feat,
                                        const int* __restrict__ src,
                                        const int* __restrict__ dst,
                                        const float* __restrict__ p,
                                        const float* __restrict__ s,
                                        float* __restrict__ out, int n_edges) {
    int g = blockIdx.x * blockDim.x + threadIdx.x;
    int e = g >> 5;
    int lane = g & 31;
    if (e >= n_edges) return;
    int u = src[e];
    int v = dst[e];
    float w = p[e] / s[v];
    atomicAdd(&out[(size_t)v * D_FEAT + lane], feat[(size_t)u * D_FEAT + lane] * w);
}

extern "C" void kernel_launch(void* const* d_in, const int* in_sizes, int n_in,
                              void* d_out, int out_size, void* d_ws, size_t ws_size,
                              hipStream_t stream) {
    const float* feat = (const float*)d_in[0];
    const float* beta = (const float*)d_in[1];
    const int*   src  = (const int*)d_in[2];
    const int*   dst  = (const int*)d_in[3];
    float* out = (float*)d_out;

    int n_nodes = in_sizes[0] / D_FEAT;
    int n_edges = in_sizes[2];
    int nb = (n_nodes + BUCKET_NODES - 1) / BUCKET_NODES;
    int nchunk = (n_edges + CHUNK_E - 1) / CHUNK_E;

    // bucket-sort path ws (4B elems):
    // nfb[N*32 bf16] | inv_norm[N] | bucket_base[nb+1] | total[MAX_NB]
    //   | chunk_hist[nb*nchunk] | recs[E]
    size_t nfb_bytes = (size_t)n_nodes * D_FEAT * 2;
    size_t need_sort = nfb_bytes +
                       ((size_t)n_nodes + (nb + 1) + MAX_NB +
                        (size_t)nb * nchunk + (size_t)n_edges) * 4;
    size_t need_ll = nfb_bytes + (size_t)n_nodes * 8 + (size_t)n_edges * 8;

    bool sort_ok = (ws_size >= need_sort) && (nb <= MAX_NB) &&
                   (n_nodes <= (1 << 24));

    if (sort_ok) {
        unsigned short* nfb = (unsigned short*)d_ws;
        float* inv_norm   = (float*)((char*)d_ws + nfb_bytes);
        int* bucket_base  = (int*)(inv_norm + n_nodes);
        int* total        = bucket_base + (nb + 1);
        int* chunk_hist   = total + MAX_NB;
        int* recs         = chunk_hist + (size_t)nb * nchunk;

        {
            int tt = n_nodes * 8;
            prep_kernel<<<(tt + 255) / 256, 256, 0, stream>>>(feat, nfb, inv_norm, n_nodes);
        }
        hist_kernel<<<nchunk, 256, 0, stream>>>(dst, chunk_hist, n_edges, nb, nchunk);
        col_prefix_kernel<<<(nb + 255) / 256, 256, 0, stream>>>(chunk_hist, total, nchunk, nb);
        base_scan_kernel<<<1, 256, 0, stream>>>(total, bucket_base, nb, n_edges);
        scatter_kernel<<<nchunk, 256, 0, stream>>>(src, dst, chunk_hist, bucket_base,
                                                   recs, n_edges, nb, nchunk);
        bucket_aggregate_kernel<<<nb, 256, 0, stream>>>(
            nfb, inv_norm, bucket_base, recs, beta, out, n_nodes);
    } else if (ws_size >= need_ll) {
        unsigned short* nfb = (unsigned short*)d_ws;
        float* inv_norm = (float*)((char*)d_ws + nfb_bytes);
        int*   head     = (int*)(inv_norm + n_nodes);
        int2*  rec      = (int2*)(head + n_nodes);

        hipMemsetAsync(head, 0xFF, (size_t)n_nodes * sizeof(int), stream);
        {
            int tt = n_nodes * 8;
            prep_kernel<<<(tt + 255) / 256, 256, 0, stream>>>(feat, nfb, inv_norm, n_nodes);
        }
        link_packed_kernel<<<2048, 256, 0, stream>>>(src, dst, head, rec, n_edges);
        {
            int tt = n_nodes * 4;
            fused_chase_bf16_kernel<<<(tt + 255) / 256, 256, 0, stream>>>(
                nfb, inv_norm, head, rec, beta, out, n_nodes);
        }
    } else {
        float* inv_norm = (float*)d_ws;
        float* s_sum    = inv_norm + n_nodes;
        float* p        = s_sum + n_nodes;

        hipMemsetAsync(s_sum, 0, (size_t)n_nodes * sizeof(float), stream);
        hipMemsetAsync(out, 0, (size_t)out_size * sizeof(float), stream);

        {
            int tt = n_nodes * 8;
            node_invnorm_kernel<<<(tt + 255) / 256, 256, 0, stream>>>(feat, inv_norm, n_nodes);
        }
        {
            long long tt = (long long)n_edges * 8;
            edge_p_kernel<<<(int)((tt + 255) / 256), 256, 0, stream>>>(
                feat, inv_norm, src, dst, beta, p, s_sum, n_edges);
        }
        {
            long long tt = (long long)n_edges * 32;
            aggregate_atomic_kernel<<<(int)((tt + 255) / 256), 256, 0, stream>>>(
                feat, src, dst, p, s_sum, out, n_edges);
        }
    }
}

// Round 9
// 109.277 us; speedup vs baseline: 4.3119x; 1.8464x over previous
//
#include <hip/hip_runtime.h>
#include <hip/hip_bf16.h>

#define D_FEAT 32
#define BUCKET_SHIFT 7
#define BUCKET_NODES 128           // 1 << BUCKET_SHIFT
#define MAX_NB 1024                // max buckets
#define CHUNK_E 8192               // edges per sort chunk
#define REC_CHUNK 4096             // records staged in LDS per aggregate chunk

typedef __attribute__((ext_vector_type(8))) unsigned short u16x8;
typedef __attribute__((ext_vector_type(8))) float f32x8;

// round-to-nearest-even f32 -> bf16 bits
static __device__ __forceinline__ unsigned short f2bf(float x) {
    unsigned int u = __float_as_uint(x);
    u += 0x7FFFu + ((u >> 16) & 1u);
    return (unsigned short)(u >> 16);
}
static __device__ __forceinline__ float bf2f(unsigned short b) {
    return __uint_as_float((unsigned int)b << 16);
}

// ---------------------------------------------------------------------------
// K0: per-node inverse L2 norm + bf16-compressed raw feature row (one 64B
// line per row). 8 lanes/node.
// ---------------------------------------------------------------------------
__global__ void prep_kernel(const float* __restrict__ feat,
                            unsigned short* __restrict__ nfb,
                            float* __restrict__ inv_norm, int n_nodes) {
    int g = blockIdx.x * blockDim.x + threadIdx.x;
    int node = g >> 3;
    int lane = g & 7;
    if (node >= n_nodes) return;
    float4 v = reinterpret_cast<const float4*>(feat + (size_t)node * D_FEAT)[lane];
    float ss = v.x * v.x + v.y * v.y + v.z * v.z + v.w * v.w;
    #pragma unroll
    for (int m = 4; m; m >>= 1) ss += __shfl_xor(ss, m, 8);
    if (lane == 0) inv_norm[node] = 1.0f / fmaxf(sqrtf(ss), 1e-12f);
    ushort4 b;
    b.x = f2bf(v.x); b.y = f2bf(v.y); b.z = f2bf(v.z); b.w = f2bf(v.w);
    reinterpret_cast<ushort4*>(nfb + (size_t)node * D_FEAT)[lane] = b;
}

// ---------------------------------------------------------------------------
// S1: per-chunk bucket histogram (LDS only; NO global atomics).
// chunk_hist is TRANSPOSED: chunk_hist[b * nchunk + c].
// ---------------------------------------------------------------------------
__global__ __launch_bounds__(256) void hist_kernel(const int* __restrict__ dst,
                                                   int* __restrict__ chunk_hist,
                                                   int n_edges, int nb, int nchunk) {
    __shared__ int s_h[MAX_NB];
    int c = blockIdx.x;
    int t = threadIdx.x;
    for (int i = t; i < MAX_NB; i += 256) s_h[i] = 0;
    __syncthreads();
    int base = c * CHUNK_E;
    int cnt = min(CHUNK_E, n_edges - base);
    for (int k = t; k < cnt; k += 256)
        atomicAdd(&s_h[dst[base + k] >> BUCKET_SHIFT], 1);
    __syncthreads();
    for (int i = t; i < nb; i += 256)
        chunk_hist[(size_t)i * nchunk + c] = s_h[i];
}

// ---------------------------------------------------------------------------
// S2: per-bucket prefix over chunks — ONE WAVE per bucket (wave-parallel
// shuffle scan, coalesced row loads/stores). Replaces the 0.13%-occupancy
// serial version (76 us -> ~4 us).
// ---------------------------------------------------------------------------
__global__ void col_prefix_kernel(int* __restrict__ chunk_hist,
                                  int* __restrict__ total, int nchunk, int nb) {
    int wid  = (blockIdx.x * blockDim.x + threadIdx.x) >> 6;
    int lane = threadIdx.x & 63;
    if (wid >= nb) return;
    int* row = chunk_hist + (size_t)wid * nchunk;
    int run = 0;
    for (int base = 0; base < nchunk; base += 64) {
        int c = base + lane;
        int v = (c < nchunk) ? row[c] : 0;
        int incl = v;
        #pragma unroll
        for (int off = 1; off < 64; off <<= 1) {
            int n = __shfl_up(incl, off, 64);
            if (lane >= off) incl += n;
        }
        if (c < nchunk) row[c] = run + (incl - v);   // exclusive within bucket
        run += __shfl(incl, 63, 64);                 // carry (uniform)
    }
    if (lane == 0) total[wid] = run;
}

// ---------------------------------------------------------------------------
// S3: single-block exclusive scan of bucket totals -> bucket_base.
// ---------------------------------------------------------------------------
__global__ __launch_bounds__(256) void base_scan_kernel(const int* __restrict__ total,
                                                        int* __restrict__ bucket_base,
                                                        int nb, int n_edges) {
    __shared__ int s_sum[256];
    int t = threadIdx.x;
    int i0 = t * 4;
    int a0 = (i0 + 0 < nb) ? total[i0 + 0] : 0;
    int a1 = (i0 + 1 < nb) ? total[i0 + 1] : 0;
    int a2 = (i0 + 2 < nb) ? total[i0 + 2] : 0;
    int a3 = (i0 + 3 < nb) ? total[i0 + 3] : 0;
    int tsum = a0 + a1 + a2 + a3;
    s_sum[t] = tsum;
    __syncthreads();
    for (int off = 1; off < 256; off <<= 1) {
        int add = (t >= off) ? s_sum[t - off] : 0;
        __syncthreads();
        s_sum[t] += add;
        __syncthreads();
    }
    int excl = s_sum[t] - tsum;
    if (i0 + 0 < nb) bucket_base[i0 + 0] = excl;
    if (i0 + 1 < nb) bucket_base[i0 + 1] = excl + a0;
    if (i0 + 2 < nb) bucket_base[i0 + 2] = excl + a0 + a1;
    if (i0 + 3 < nb) bucket_base[i0 + 3] = excl + a0 + a1 + a2;
    if (t == 0) bucket_base[nb] = n_edges;
}

// ---------------------------------------------------------------------------
// S4: scatter. Per chunk: LDS counting sort of 8192 records by bucket, then
// copy each bucket-run to its PRECOMPUTED global slot. Zero global atomics.
// Bucket id per LDS slot is recorded at placement (s_b) -> copy-out is 3
// coalesced LDS reads, no binary search.
// ---------------------------------------------------------------------------
__global__ __launch_bounds__(256) void scatter_kernel(const int* __restrict__ src,
                                                      const int* __restrict__ dst,
                                                      const int* __restrict__ chunk_hist,
                                                      const int* __restrict__ bucket_base,
                                                      int* __restrict__ recs,
                                                      int n_edges, int nb, int nchunk) {
    __shared__ int s_cur[MAX_NB];        // hist, then run cursor
    __shared__ int s_off[MAX_NB + 1];    // exclusive offsets (+ sentinel)
    __shared__ int s_gbase[MAX_NB];      // global base of this chunk's run
    __shared__ int s_sum[256];
    __shared__ int s_rec[CHUNK_E];
    __shared__ unsigned short s_b[CHUNK_E];

    int c = blockIdx.x;
    int t = threadIdx.x;
    int base = c * CHUNK_E;
    int cnt = min(CHUNK_E, n_edges - base);

    for (int i = t; i < MAX_NB; i += 256) s_cur[i] = 0;
    __syncthreads();
    for (int k = t; k < cnt; k += 256)
        atomicAdd(&s_cur[dst[base + k] >> BUCKET_SHIFT], 1);
    __syncthreads();

    // exclusive scan of s_cur[1024] -> s_off (4 items/thread)
    int i0 = t * 4;
    int a0 = s_cur[i0], a1 = s_cur[i0 + 1], a2 = s_cur[i0 + 2], a3 = s_cur[i0 + 3];
    int tsum = a0 + a1 + a2 + a3;
    s_sum[t] = tsum;
    __syncthreads();
    for (int off = 1; off < 256; off <<= 1) {
        int add = (t >= off) ? s_sum[t - off] : 0;
        __syncthreads();
        s_sum[t] += add;
        __syncthreads();
    }
    int excl = s_sum[t] - tsum;
    s_off[i0 + 0] = excl;
    s_off[i0 + 1] = excl + a0;
    s_off[i0 + 2] = excl + a0 + a1;
    s_off[i0 + 3] = excl + a0 + a1 + a2;
    if (t == 255) s_off[MAX_NB] = excl + tsum;  // == cnt
    __syncthreads();
    for (int i = t; i < MAX_NB; i += 256) s_cur[i] = s_off[i];
    for (int i = t; i < nb; i += 256)
        s_gbase[i] = bucket_base[i] + chunk_hist[(size_t)i * nchunk + c];
    __syncthreads();

    // place records into LDS in bucket-sorted order; remember bucket per slot
    for (int k = t; k < cnt; k += 256) {
        int d = dst[base + k];
        int s = src[base + k];
        int b = d >> BUCKET_SHIFT;
        int lpos = atomicAdd(&s_cur[b], 1);
        s_rec[lpos] = (s << BUCKET_SHIFT) | (d & (BUCKET_NODES - 1));
        s_b[lpos] = (unsigned short)b;
    }
    __syncthreads();

    // copy out: fully coalesced LDS reads; runs -> contiguous global stores
    for (int i = t; i < cnt; i += 256) {
        int b = s_b[i];
        recs[s_gbase[b] + (i - s_off[b])] = s_rec[i];
    }
}

// ---------------------------------------------------------------------------
// C: per-bucket aggregation. One block per bucket; LDS counting-sort by
// dst_low, then 8-lane groups register-accumulate their nodes' runs.
// Single coalesced row write per node; no global atomics.
// ---------------------------------------------------------------------------
__global__ __launch_bounds__(256) void bucket_aggregate_kernel(
    const unsigned short* __restrict__ nfb,
    const float* __restrict__ inv_norm,
    const int* __restrict__ bucket_base,
    const int* __restrict__ recs,
    const float* __restrict__ beta,
    float* __restrict__ out, int n_nodes) {

    __shared__ int s_rec[REC_CHUNK];
    __shared__ int s_hist[BUCKET_NODES];
    __shared__ int s_off[BUCKET_NODES];

    int b = blockIdx.x;
    int node0 = b * BUCKET_NODES;
    int start = bucket_base[b];
    int end   = bucket_base[b + 1];
    int t = threadIdx.x;
    int group = t >> 3;   // 0..31
    int lane  = t & 7;
    float bscale = beta[0];

    float4 bn[4];
    float4 acc[4];
    float  ssum[4];
    #pragma unroll
    for (int r = 0; r < 4; ++r) {
        int v = node0 + r * 32 + group;
        acc[r] = make_float4(0.f, 0.f, 0.f, 0.f);
        ssum[r] = 0.f;
        bn[r] = make_float4(0.f, 0.f, 0.f, 0.f);
        if (v < n_nodes) {
            ushort4 braw = reinterpret_cast<const ushort4*>(nfb + (size_t)v * D_FEAT)[lane];
            float invv = inv_norm[v];
            bn[r].x = bf2f(braw.x) * invv;
            bn[r].y = bf2f(braw.y) * invv;
            bn[r].z = bf2f(braw.z) * invv;
            bn[r].w = bf2f(braw.w) * invv;
        }
    }

    for (int cbase = start; cbase < end; cbase += REC_CHUNK) {
        int cnt = min(REC_CHUNK, end - cbase);

        if (t < BUCKET_NODES) s_hist[t] = 0;
        __syncthreads();
        for (int i = t; i < cnt; i += 256)
            atomicAdd(&s_hist[recs[cbase + i] & (BUCKET_NODES - 1)], 1);
        __syncthreads();

        if (t < BUCKET_NODES) s_off[t] = s_hist[t];
        __syncthreads();
        for (int off = 1; off < BUCKET_NODES; off <<= 1) {
            int add = (t >= off && t < BUCKET_NODES) ? s_off[t - off] : 0;
            __syncthreads();
            if (t < BUCKET_NODES) s_off[t] += add;
            __syncthreads();
        }
        if (t < BUCKET_NODES) s_hist[t] = s_off[t] - s_hist[t];  // run cursor
        __syncthreads();
        for (int i = t; i < cnt; i += 256) {
            int r = recs[cbase + i];
            int pos = atomicAdd(&s_hist[r & (BUCKET_NODES - 1)], 1);
            s_rec[pos] = r;
        }
        __syncthreads();

        #pragma unroll
        for (int r = 0; r < 4; ++r) {
            int dl = r * 32 + group;
            int rs = dl ? s_off[dl - 1] : 0;
            int re = s_off[dl];
            for (int i = rs; i < re; ++i) {
                int rec = s_rec[i];                 // uniform in group: broadcast
                int u = ((unsigned)rec) >> BUCKET_SHIFT;
                float invu = inv_norm[u];
                ushort4 araw = reinterpret_cast<const ushort4*>(nfb + (size_t)u * D_FEAT)[lane];
                float4 a;
                a.x = bf2f(araw.x); a.y = bf2f(araw.y);
                a.z = bf2f(araw.z); a.w = bf2f(araw.w);
                float d = a.x * bn[r].x;
                d = fmaf(a.y, bn[r].y, d);
                d = fmaf(a.z, bn[r].z, d);
                d = fmaf(a.w, bn[r].w, d);
                d += __shfl_xor(d, 1, 8);
                d += __shfl_xor(d, 2, 8);
                d += __shfl_xor(d, 4, 8);
                float pe = __expf(bscale * d * invu);  // |arg|<=beta: no max-shift
                acc[r].x = fmaf(pe, a.x, acc[r].x);
                acc[r].y = fmaf(pe, a.y, acc[r].y);
                acc[r].z = fmaf(pe, a.z, acc[r].z);
                acc[r].w = fmaf(pe, a.w, acc[r].w);
                ssum[r] += pe;
            }
        }
        __syncthreads();
    }

    #pragma unroll
    for (int r = 0; r < 4; ++r) {
        int v = node0 + r * 32 + group;
        if (v < n_nodes) {
            float inv_s = (ssum[r] > 0.f) ? (1.0f / ssum[r]) : 0.0f;
            float4 o = make_float4(acc[r].x * inv_s, acc[r].y * inv_s,
                                   acc[r].z * inv_s, acc[r].w * inv_s);
            reinterpret_cast<float4*>(out + (size_t)v * D_FEAT)[lane] = o;
        }
    }
}

// ---------------------------------------------------------------------------
// Fallback 1 (proven R6): packed linked-list + bf16 chase.
// ---------------------------------------------------------------------------
__global__ void link_packed_kernel(const int* __restrict__ src,
                                   const int* __restrict__ dst,
                                   int* __restrict__ head,
                                   int2* __restrict__ rec, int n_edges) {
    int stride = gridDim.x * blockDim.x;
    for (int e = blockIdx.x * blockDim.x + threadIdx.x; e < n_edges; e += stride) {
        int d = dst[e];
        int s = src[e];
        int old = atomicExch(&head[d], e);
        rec[e] = make_int2(old, s);
    }
}

__global__ void fused_chase_bf16_kernel(const unsigned short* __restrict__ nfb,
                                        const float* __restrict__ inv_norm,
                                        const int* __restrict__ head,
                                        const int2* __restrict__ rec,
                                        const float* __restrict__ beta,
                                        float* __restrict__ out, int n_nodes) {
    int g = blockIdx.x * blockDim.x + threadIdx.x;
    int node = g >> 2;
    int lane = g & 3;
    if (node >= n_nodes) return;

    float bscale = beta[0];
    float invv = inv_norm[node];
    u16x8 braw = reinterpret_cast<const u16x8*>(nfb + (size_t)node * D_FEAT)[lane];
    f32x8 bn;
    #pragma unroll
    for (int j = 0; j < 8; ++j) bn[j] = bf2f(braw[j]) * invv;

    f32x8 acc;
    #pragma unroll
    for (int j = 0; j < 8; ++j) acc[j] = 0.f;
    float ssum = 0.f;

    int e = head[node];
    while (e >= 0) {
        int2 r = rec[e];
        int en = r.x, u = r.y;
        float invu = inv_norm[u];
        u16x8 araw = reinterpret_cast<const u16x8*>(nfb + (size_t)u * D_FEAT)[lane];
        f32x8 a;
        float d = 0.f;
        #pragma unroll
        for (int j = 0; j < 8; ++j) {
            a[j] = bf2f(araw[j]);
            d = fmaf(a[j], bn[j], d);
        }
        d += __shfl_xor(d, 1, 4);
        d += __shfl_xor(d, 2, 4);
        float pe = __expf(bscale * d * invu);
        #pragma unroll
        for (int j = 0; j < 8; ++j) acc[j] = fmaf(pe, a[j], acc[j]);
        ssum += pe;
        e = en;
    }

    float inv_s = (ssum > 0.f) ? (1.0f / ssum) : 0.0f;
    float* op = out + (size_t)node * D_FEAT + lane * 8;
    reinterpret_cast<float4*>(op)[0] =
        make_float4(acc[0] * inv_s, acc[1] * inv_s, acc[2] * inv_s, acc[3] * inv_s);
    reinterpret_cast<float4*>(op)[1] =
        make_float4(acc[4] * inv_s, acc[5] * inv_s, acc[6] * inv_s, acc[7] * inv_s);
}

// ---------------------------------------------------------------------------
// Fallback 2 (tiny ws): f32 atomic path.
// ---------------------------------------------------------------------------
__global__ void node_invnorm_kernel(const float* __restrict__ feat,
                                    float* __restrict__ inv_norm, int n_nodes) {
    int g = blockIdx.x * blockDim.x + threadIdx.x;
    int node = g >> 3;
    int lane = g & 7;
    if (node >= n_nodes) return;
    float4 v = reinterpret_cast<const float4*>(feat + (size_t)node * D_FEAT)[lane];
    float ss = v.x * v.x + v.y * v.y + v.z * v.z + v.w * v.w;
    #pragma unroll
    for (int m = 4; m; m >>= 1) ss += __shfl_xor(ss, m, 8);
    if (lane == 0) inv_norm[node] = 1.0f / fmaxf(sqrtf(ss), 1e-12f);
}

__global__ void edge_p_kernel(const float* __restrict__ feat,
                              const float* __restrict__ inv_norm,
                              const int* __restrict__ src,
                              const int* __restrict__ dst,
                              const float* __restrict__ beta,
                              float* __restrict__ p, float* __restrict__ s,
                              int n_edges) {
    int g = blockIdx.x * blockDim.x + threadIdx.x;
    int e = g >> 3;
    int lane = g & 7;
    if (e >= n_edges) return;
    int u = src[e];
    int v = dst[e];
    float4 a = reinterpret_cast<const float4*>(feat + (size_t)u * D_FEAT)[lane];
    float4 b = reinterpret_cast<const float4*>(feat + (size_t)v * D_FEAT)[lane];
    float d = a.x * b.x;
    d = fmaf(a.y, b.y, d);
    d = fmaf(a.z, b.z, d);
    d = fmaf(a.w, b.w, d);
    #pragma unroll
    for (int m = 4; m; m >>= 1) d += __shfl_xor(d, m, 8);
    if (lane == 0) {
        float pe = __expf(beta[0] * d * inv_norm[u] * inv_norm[v]);
        p[e] = pe;
        atomicAdd(&s[v], pe);
    }
}

__global__ void aggregate_atomic_kernel(const float* __restrict__ feat,
                                        const int* __restrict__ src,
                                        const int* __restrict__ dst,
                                        const float* __restrict__ p,
                                        const float* __restrict__ s,
                                        float* __restrict__ out, int n_edges) {
    int g = blockIdx.x * blockDim.x + threadIdx.x;
    int e = g >> 5;
    int lane = g & 31;
    if (e >= n_edges) return;
    int u = src[e];
    int v = dst[e];
    float w = p[e] / s[v];
    atomicAdd(&out[(size_t)v * D_FEAT + lane], feat[(size_t)u * D_FEAT + lane] * w);
}

extern "C" void kernel_launch(void* const* d_in, const int* in_sizes, int n_in,
                              void* d_out, int out_size, void* d_ws, size_t ws_size,
                              hipStream_t stream) {
    const float* feat = (const float*)d_in[0];
    const float* beta = (const float*)d_in[1];
    const int*   src  = (const int*)d_in[2];
    const int*   dst  = (const int*)d_in[3];
    float* out = (float*)d_out;

    int n_nodes = in_sizes[0] / D_FEAT;
    int n_edges = in_sizes[2];
    int nb = (n_nodes + BUCKET_NODES - 1) / BUCKET_NODES;
    int nchunk = (n_edges + CHUNK_E - 1) / CHUNK_E;

    // bucket-sort path ws (4B elems):
    // nfb[N*32 bf16] | inv_norm[N] | bucket_base[nb+1] | total[MAX_NB]
    //   | chunk_hist[nb*nchunk] | recs[E]
    size_t nfb_bytes = (size_t)n_nodes * D_FEAT * 2;
    size_t need_sort = nfb_bytes +
                       ((size_t)n_nodes + (nb + 1) + MAX_NB +
                        (size_t)nb * nchunk + (size_t)n_edges) * 4;
    size_t need_ll = nfb_bytes + (size_t)n_nodes * 8 + (size_t)n_edges * 8;

    bool sort_ok = (ws_size >= need_sort) && (nb <= MAX_NB) &&
                   (n_nodes <= (1 << 24));

    if (sort_ok) {
        unsigned short* nfb = (unsigned short*)d_ws;
        float* inv_norm   = (float*)((char*)d_ws + nfb_bytes);
        int* bucket_base  = (int*)(inv_norm + n_nodes);
        int* total        = bucket_base + (nb + 1);
        int* chunk_hist   = total + MAX_NB;
        int* recs         = chunk_hist + (size_t)nb * nchunk;

        {
            int tt = n_nodes * 8;
            prep_kernel<<<(tt + 255) / 256, 256, 0, stream>>>(feat, nfb, inv_norm, n_nodes);
        }
        hist_kernel<<<nchunk, 256, 0, stream>>>(dst, chunk_hist, n_edges, nb, nchunk);
        {
            int waves = (nb + 3) / 4;   // 4 waves per 256-thr block
            col_prefix_kernel<<<waves, 256, 0, stream>>>(chunk_hist, total, nchunk, nb);
        }
        base_scan_kernel<<<1, 256, 0, stream>>>(total, bucket_base, nb, n_edges);
        scatter_kernel<<<nchunk, 256, 0, stream>>>(src, dst, chunk_hist, bucket_base,
                                                   recs, n_edges, nb, nchunk);
        bucket_aggregate_kernel<<<nb, 256, 0, stream>>>(
            nfb, inv_norm, bucket_base, recs, beta, out, n_nodes);
    } else if (ws_size >= need_ll) {
        unsigned short* nfb = (unsigned short*)d_ws;
        float* inv_norm = (float*)((char*)d_ws + nfb_bytes);
        int*   head     = (int*)(inv_norm + n_nodes);
        int2*  rec      = (int2*)(head + n_nodes);

        hipMemsetAsync(head, 0xFF, (size_t)n_nodes * sizeof(int), stream);
        {
            int tt = n_nodes * 8;
            prep_kernel<<<(tt + 255) / 256, 256, 0, stream>>>(feat, nfb, inv_norm, n_nodes);
        }
        link_packed_kernel<<<2048, 256, 0, stream>>>(src, dst, head, rec, n_edges);
        {
            int tt = n_nodes * 4;
            fused_chase_bf16_kernel<<<(tt + 255) / 256, 256, 0, stream>>>(
                nfb, inv_norm, head, rec, beta, out, n_nodes);
        }
    } else {
        float* inv_norm = (float*)d_ws;
        float* s_sum    = inv_norm + n_nodes;
        float* p        = s_sum + n_nodes;

        hipMemsetAsync(s_sum, 0, (size_t)n_nodes * sizeof(float), stream);
        hipMemsetAsync(out, 0, (size_t)out_size * sizeof(float), stream);

        {
            int tt = n_nodes * 8;
            node_invnorm_kernel<<<(tt + 255) / 256, 256, 0, stream>>>(feat, inv_norm, n_nodes);
        }
        {
            long long tt = (long long)n_edges * 8;
            edge_p_kernel<<<(int)((tt + 255) / 256), 256, 0, stream>>>(
                feat, inv_norm, src, dst, beta, p, s_sum, n_edges);
        }
        {
            long long tt = (long long)n_edges * 32;
            aggregate_atomic_kernel<<<(int)((tt + 255) / 256), 256, 0, stream>>>(
                feat, src, dst, p, s_sum, out, n_edges);
        }
    }
}

// Round 10
// 90.254 us; speedup vs baseline: 5.2208x; 1.2108x over previous
//
#include <hip/hip_runtime.h>
#include <hip/hip_bf16.h>

#define D_FEAT 32
#define BUCKET_SHIFT 6
#define BUCKET_NODES 64            // 1 << BUCKET_SHIFT
#define MAX_NB 2048                // max buckets
#define CHUNK_E 4096               // edges per sort chunk (keeps scatter LDS < 64KB)
#define REC_CHUNK 4096             // records staged in LDS per aggregate chunk

typedef __attribute__((ext_vector_type(8))) unsigned short u16x8;
typedef __attribute__((ext_vector_type(8))) float f32x8;

// round-to-nearest-even f32 -> bf16 bits
static __device__ __forceinline__ unsigned short f2bf(float x) {
    unsigned int u = __float_as_uint(x);
    u += 0x7FFFu + ((u >> 16) & 1u);
    return (unsigned short)(u >> 16);
}
static __device__ __forceinline__ float bf2f(unsigned short b) {
    return __uint_as_float((unsigned int)b << 16);
}

// ---------------------------------------------------------------------------
// K0: per-node inverse L2 norm + bf16-compressed raw feature row (one 64B
// line per row). 8 lanes/node.
// ---------------------------------------------------------------------------
__global__ void prep_kernel(const float* __restrict__ feat,
                            unsigned short* __restrict__ nfb,
                            float* __restrict__ inv_norm, int n_nodes) {
    int g = blockIdx.x * blockDim.x + threadIdx.x;
    int node = g >> 3;
    int lane = g & 7;
    if (node >= n_nodes) return;
    float4 v = reinterpret_cast<const float4*>(feat + (size_t)node * D_FEAT)[lane];
    float ss = v.x * v.x + v.y * v.y + v.z * v.z + v.w * v.w;
    #pragma unroll
    for (int m = 4; m; m >>= 1) ss += __shfl_xor(ss, m, 8);
    if (lane == 0) inv_norm[node] = 1.0f / fmaxf(sqrtf(ss), 1e-12f);
    ushort4 b;
    b.x = f2bf(v.x); b.y = f2bf(v.y); b.z = f2bf(v.z); b.w = f2bf(v.w);
    reinterpret_cast<ushort4*>(nfb + (size_t)node * D_FEAT)[lane] = b;
}

// ---------------------------------------------------------------------------
// S1: per-chunk bucket histogram (LDS only; NO global atomics).
// chunk_hist is TRANSPOSED: chunk_hist[b * nchunk + c].
// ---------------------------------------------------------------------------
__global__ __launch_bounds__(256) void hist_kernel(const int* __restrict__ dst,
                                                   int* __restrict__ chunk_hist,
                                                   int n_edges, int nb, int nchunk) {
    __shared__ int s_h[MAX_NB];
    int c = blockIdx.x;
    int t = threadIdx.x;
    for (int i = t; i < MAX_NB; i += 256) s_h[i] = 0;
    __syncthreads();
    int base = c * CHUNK_E;
    int cnt = min(CHUNK_E, n_edges - base);
    for (int k = t; k < cnt; k += 256)
        atomicAdd(&s_h[dst[base + k] >> BUCKET_SHIFT], 1);
    __syncthreads();
    for (int i = t; i < nb; i += 256)
        chunk_hist[(size_t)i * nchunk + c] = s_h[i];
}

// ---------------------------------------------------------------------------
// S2: per-bucket prefix over chunks — ONE WAVE per bucket (wave-parallel
// shuffle scan, coalesced row loads/stores).
// ---------------------------------------------------------------------------
__global__ void col_prefix_kernel(int* __restrict__ chunk_hist,
                                  int* __restrict__ total, int nchunk, int nb) {
    int wid  = (blockIdx.x * blockDim.x + threadIdx.x) >> 6;
    int lane = threadIdx.x & 63;
    if (wid >= nb) return;
    int* row = chunk_hist + (size_t)wid * nchunk;
    int run = 0;
    for (int base = 0; base < nchunk; base += 64) {
        int c = base + lane;
        int v = (c < nchunk) ? row[c] : 0;
        int incl = v;
        #pragma unroll
        for (int off = 1; off < 64; off <<= 1) {
            int n = __shfl_up(incl, off, 64);
            if (lane >= off) incl += n;
        }
        if (c < nchunk) row[c] = run + (incl - v);   // exclusive within bucket
        run += __shfl(incl, 63, 64);                 // carry (uniform)
    }
    if (lane == 0) total[wid] = run;
}

// ---------------------------------------------------------------------------
// S3: single-block exclusive scan of bucket totals (8 items/thread, 2048 max).
// ---------------------------------------------------------------------------
__global__ __launch_bounds__(256) void base_scan_kernel(const int* __restrict__ total,
                                                        int* __restrict__ bucket_base,
                                                        int nb, int n_edges) {
    __shared__ int s_sum[256];
    int t = threadIdx.x;
    int i0 = t * 8;
    int a[8];
    int tsum = 0;
    #pragma unroll
    for (int j = 0; j < 8; ++j) {
        a[j] = (i0 + j < nb) ? total[i0 + j] : 0;
        tsum += a[j];
    }
    s_sum[t] = tsum;
    __syncthreads();
    for (int off = 1; off < 256; off <<= 1) {
        int add = (t >= off) ? s_sum[t - off] : 0;
        __syncthreads();
        s_sum[t] += add;
        __syncthreads();
    }
    int run = s_sum[t] - tsum;
    #pragma unroll
    for (int j = 0; j < 8; ++j) {
        if (i0 + j < nb) bucket_base[i0 + j] = run;
        run += a[j];
    }
    if (t == 0) bucket_base[nb] = n_edges;
}

// ---------------------------------------------------------------------------
// S4: scatter. Per chunk: LDS counting sort of CHUNK_E records by bucket,
// then copy each bucket-run to its PRECOMPUTED global slot. Zero global
// atomics. Bucket id per slot recorded at placement -> coalesced copy-out.
// LDS: 8+8+8+1+16+8 = ~49KB.
// ---------------------------------------------------------------------------
__global__ __launch_bounds__(256) void scatter_kernel(const int* __restrict__ src,
                                                      const int* __restrict__ dst,
                                                      const int* __restrict__ chunk_hist,
                                                      const int* __restrict__ bucket_base,
                                                      int* __restrict__ recs,
                                                      int n_edges, int nb, int nchunk) {
    __shared__ int s_cur[MAX_NB];        // hist, then run cursor
    __shared__ int s_off[MAX_NB + 1];    // exclusive offsets (+ sentinel)
    __shared__ int s_gbase[MAX_NB];      // global base of this chunk's run
    __shared__ int s_sum[256];
    __shared__ int s_rec[CHUNK_E];
    __shared__ unsigned short s_b[CHUNK_E];

    int c = blockIdx.x;
    int t = threadIdx.x;
    int base = c * CHUNK_E;
    int cnt = min(CHUNK_E, n_edges - base);

    for (int i = t; i < MAX_NB; i += 256) s_cur[i] = 0;
    __syncthreads();
    for (int k = t; k < cnt; k += 256)
        atomicAdd(&s_cur[dst[base + k] >> BUCKET_SHIFT], 1);
    __syncthreads();

    // exclusive scan of s_cur[MAX_NB] -> s_off (8 items/thread)
    int i0 = t * 8;
    int a[8];
    int tsum = 0;
    #pragma unroll
    for (int j = 0; j < 8; ++j) { a[j] = s_cur[i0 + j]; tsum += a[j]; }
    s_sum[t] = tsum;
    __syncthreads();
    for (int off = 1; off < 256; off <<= 1) {
        int add = (t >= off) ? s_sum[t - off] : 0;
        __syncthreads();
        s_sum[t] += add;
        __syncthreads();
    }
    int run = s_sum[t] - tsum;
    #pragma unroll
    for (int j = 0; j < 8; ++j) { s_off[i0 + j] = run; run += a[j]; }
    if (t == 255) s_off[MAX_NB] = run;  // == cnt
    __syncthreads();
    for (int i = t; i < MAX_NB; i += 256) s_cur[i] = s_off[i];
    for (int i = t; i < nb; i += 256)
        s_gbase[i] = bucket_base[i] + chunk_hist[(size_t)i * nchunk + c];
    __syncthreads();

    // place records into LDS in bucket-sorted order; remember bucket per slot
    for (int k = t; k < cnt; k += 256) {
        int d = dst[base + k];
        int s = src[base + k];
        int b = d >> BUCKET_SHIFT;
        int lpos = atomicAdd(&s_cur[b], 1);
        s_rec[lpos] = (s << BUCKET_SHIFT) | (d & (BUCKET_NODES - 1));
        s_b[lpos] = (unsigned short)b;
    }
    __syncthreads();

    // copy out: coalesced LDS reads; runs -> contiguous global stores
    for (int i = t; i < cnt; i += 256) {
        int b = s_b[i];
        recs[s_gbase[b] + (i - s_off[b])] = s_rec[i];
    }
}

// ---------------------------------------------------------------------------
// C: per-bucket aggregation. One block per 64-node bucket; LDS counting-sort
// by dst_low, then 32 groups of 8 lanes register-accumulate their 2 owned
// nodes' runs. Single coalesced row write per node; no global atomics.
// ---------------------------------------------------------------------------
__global__ __launch_bounds__(256) void bucket_aggregate_kernel(
    const unsigned short* __restrict__ nfb,
    const float* __restrict__ inv_norm,
    const int* __restrict__ bucket_base,
    const int* __restrict__ recs,
    const float* __restrict__ beta,
    float* __restrict__ out, int n_nodes) {

    __shared__ int s_rec[REC_CHUNK];
    __shared__ int s_hist[BUCKET_NODES];
    __shared__ int s_off[BUCKET_NODES];

    int b = blockIdx.x;
    int node0 = b * BUCKET_NODES;
    int start = bucket_base[b];
    int end   = bucket_base[b + 1];
    int t = threadIdx.x;
    int group = t >> 3;   // 0..31
    int lane  = t & 7;
    float bscale = beta[0];

    float4 bn[2];
    float4 acc[2];
    float  ssum[2];
    #pragma unroll
    for (int r = 0; r < 2; ++r) {
        int v = node0 + r * 32 + group;
        acc[r] = make_float4(0.f, 0.f, 0.f, 0.f);
        ssum[r] = 0.f;
        bn[r] = make_float4(0.f, 0.f, 0.f, 0.f);
        if (v < n_nodes) {
            ushort4 braw = reinterpret_cast<const ushort4*>(nfb + (size_t)v * D_FEAT)[lane];
            float invv = inv_norm[v];
            bn[r].x = bf2f(braw.x) * invv;
            bn[r].y = bf2f(braw.y) * invv;
            bn[r].z = bf2f(braw.z) * invv;
            bn[r].w = bf2f(braw.w) * invv;
        }
    }

    for (int cbase = start; cbase < end; cbase += REC_CHUNK) {
        int cnt = min(REC_CHUNK, end - cbase);

        if (t < BUCKET_NODES) s_hist[t] = 0;
        __syncthreads();
        for (int i = t; i < cnt; i += 256)
            atomicAdd(&s_hist[recs[cbase + i] & (BUCKET_NODES - 1)], 1);
        __syncthreads();

        if (t < BUCKET_NODES) s_off[t] = s_hist[t];
        __syncthreads();
        for (int off = 1; off < BUCKET_NODES; off <<= 1) {
            int add = (t >= off && t < BUCKET_NODES) ? s_off[t - off] : 0;
            __syncthreads();
            if (t < BUCKET_NODES) s_off[t] += add;
            __syncthreads();
        }
        if (t < BUCKET_NODES) s_hist[t] = s_off[t] - s_hist[t];  // run cursor
        __syncthreads();
        for (int i = t; i < cnt; i += 256) {
            int r = recs[cbase + i];
            int pos = atomicAdd(&s_hist[r & (BUCKET_NODES - 1)], 1);
            s_rec[pos] = r;
        }
        __syncthreads();

        #pragma unroll
        for (int r = 0; r < 2; ++r) {
            int dl = r * 32 + group;
            int rs = dl ? s_off[dl - 1] : 0;
            int re = s_off[dl];
            for (int i = rs; i < re; ++i) {
                int rec = s_rec[i];                 // uniform in group: broadcast
                int u = ((unsigned)rec) >> BUCKET_SHIFT;
                float invu = inv_norm[u];
                ushort4 araw = reinterpret_cast<const ushort4*>(nfb + (size_t)u * D_FEAT)[lane];
                float4 a;
                a.x = bf2f(araw.x); a.y = bf2f(araw.y);
                a.z = bf2f(araw.z); a.w = bf2f(araw.w);
                float d = a.x * bn[r].x;
                d = fmaf(a.y, bn[r].y, d);
                d = fmaf(a.z, bn[r].z, d);
                d = fmaf(a.w, bn[r].w, d);
                d += __shfl_xor(d, 1, 8);
                d += __shfl_xor(d, 2, 8);
                d += __shfl_xor(d, 4, 8);
                float pe = __expf(bscale * d * invu);  // |arg|<=beta: no max-shift
                acc[r].x = fmaf(pe, a.x, acc[r].x);
                acc[r].y = fmaf(pe, a.y, acc[r].y);
                acc[r].z = fmaf(pe, a.z, acc[r].z);
                acc[r].w = fmaf(pe, a.w, acc[r].w);
                ssum[r] += pe;
            }
        }
        __syncthreads();
    }

    #pragma unroll
    for (int r = 0; r < 2; ++r) {
        int v = node0 + r * 32 + group;
        if (v < n_nodes) {
            float inv_s = (ssum[r] > 0.f) ? (1.0f / ssum[r]) : 0.0f;
            float4 o = make_float4(acc[r].x * inv_s, acc[r].y * inv_s,
                                   acc[r].z * inv_s, acc[r].w * inv_s);
            reinterpret_cast<float4*>(out + (size_t)v * D_FEAT)[lane] = o;
        }
    }
}

// ---------------------------------------------------------------------------
// Fallback 1 (proven R6): packed linked-list + bf16 chase.
// ---------------------------------------------------------------------------
__global__ void link_packed_kernel(const int* __restrict__ src,
                                   const int* __restrict__ dst,
                                   int* __restrict__ head,
                                   int2* __restrict__ rec, int n_edges) {
    int stride = gridDim.x * blockDim.x;
    for (int e = blockIdx.x * blockDim.x + threadIdx.x; e < n_edges; e += stride) {
        int d = dst[e];
        int s = src[e];
        int old = atomicExch(&head[d], e);
        rec[e] = make_int2(old, s);
    }
}

__global__ void fused_chase_bf16_kernel(const unsigned short* __restrict__ nfb,
                                        const float* __restrict__ inv_norm,
                                        const int* __restrict__ head,
                                        const int2* __restrict__ rec,
                                        const float* __restrict__ beta,
                                        float* __restrict__ out, int n_nodes) {
    int g = blockIdx.x * blockDim.x + threadIdx.x;
    int node = g >> 2;
    int lane = g & 3;
    if (node >= n_nodes) return;

    float bscale = beta[0];
    float invv = inv_norm[node];
    u16x8 braw = reinterpret_cast<const u16x8*>(nfb + (size_t)node * D_FEAT)[lane];
    f32x8 bn;
    #pragma unroll
    for (int j = 0; j < 8; ++j) bn[j] = bf2f(braw[j]) * invv;

    f32x8 acc;
    #pragma unroll
    for (int j = 0; j < 8; ++j) acc[j] = 0.f;
    float ssum = 0.f;

    int e = head[node];
    while (e >= 0) {
        int2 r = rec[e];
        int en = r.x, u = r.y;
        float invu = inv_norm[u];
        u16x8 araw = reinterpret_cast<const u16x8*>(nfb + (size_t)u * D_FEAT)[lane];
        f32x8 a;
        float d = 0.f;
        #pragma unroll
        for (int j = 0; j < 8; ++j) {
            a[j] = bf2f(araw[j]);
            d = fmaf(a[j], bn[j], d);
        }
        d += __shfl_xor(d, 1, 4);
        d += __shfl_xor(d, 2, 4);
        float pe = __expf(bscale * d * invu);
        #pragma unroll
        for (int j = 0; j < 8; ++j) acc[j] = fmaf(pe, a[j], acc[j]);
        ssum += pe;
        e = en;
    }

    float inv_s = (ssum > 0.f) ? (1.0f / ssum) : 0.0f;
    float* op = out + (size_t)node * D_FEAT + lane * 8;
    reinterpret_cast<float4*>(op)[0] =
        make_float4(acc[0] * inv_s, acc[1] * inv_s, acc[2] * inv_s, acc[3] * inv_s);
    reinterpret_cast<float4*>(op)[1] =
        make_float4(acc[4] * inv_s, acc[5] * inv_s, acc[6] * inv_s, acc[7] * inv_s);
}

// ---------------------------------------------------------------------------
// Fallback 2 (tiny ws): f32 atomic path.
// ---------------------------------------------------------------------------
__global__ void node_invnorm_kernel(const float* __restrict__ feat,
                                    float* __restrict__ inv_norm, int n_nodes) {
    int g = blockIdx.x * blockDim.x + threadIdx.x;
    int node = g >> 3;
    int lane = g & 7;
    if (node >= n_nodes) return;
    float4 v = reinterpret_cast<const float4*>(feat + (size_t)node * D_FEAT)[lane];
    float ss = v.x * v.x + v.y * v.y + v.z * v.z + v.w * v.w;
    #pragma unroll
    for (int m = 4; m; m >>= 1) ss += __shfl_xor(ss, m, 8);
    if (lane == 0) inv_norm[node] = 1.0f / fmaxf(sqrtf(ss), 1e-12f);
}

__global__ void edge_p_kernel(const float* __restrict__ feat,
                              const float* __restrict__ inv_norm,
                              const int* __restrict__ src,
                              const int* __restrict__ dst,
                              const float* __restrict__ beta,
                              float* __restrict__ p, float* __restrict__ s,
                              int n_edges) {
    int g = blockIdx.x * blockDim.x + threadIdx.x;
    int e = g >> 3;
    int lane = g & 7;
    if (e >= n_edges) return;
    int u = src[e];
    int v = dst[e];
    float4 a = reinterpret_cast<const float4*>(feat + (size_t)u * D_FEAT)[lane];
    float4 b = reinterpret_cast<const float4*>(feat + (size_t)v * D_FEAT)[lane];
    float d = a.x * b.x;
    d = fmaf(a.y, b.y, d);
    d = fmaf(a.z, b.z, d);
    d = fmaf(a.w, b.w, d);
    #pragma unroll
    for (int m = 4; m; m >>= 1) d += __shfl_xor(d, m, 8);
    if (lane == 0) {
        float pe = __expf(beta[0] * d * inv_norm[u] * inv_norm[v]);
        p[e] = pe;
        atomicAdd(&s[v], pe);
    }
}

__global__ void aggregate_atomic_kernel(const float* __restrict__ feat,
                                        const int* __restrict__ src,
                                        const int* __restrict__ dst,
                                        const float* __restrict__ p,
                                        const float* __restrict__ s,
                                        float* __restrict__ out, int n_edges) {
    int g = blockIdx.x * blockDim.x + threadIdx.x;
    int e = g >> 5;
    int lane = g & 31;
    if (e >= n_edges) return;
    int u = src[e];
    int v = dst[e];
    float w = p[e] / s[v];
    atomicAdd(&out[(size_t)v * D_FEAT + lane], feat[(size_t)u * D_FEAT + lane] * w);
}

extern "C" void kernel_launch(void* const* d_in, const int* in_sizes, int n_in,
                              void* d_out, int out_size, void* d_ws, size_t ws_size,
                              hipStream_t stream) {
    const float* feat = (const float*)d_in[0];
    const float* beta = (const float*)d_in[1];
    const int*   src  = (const int*)d_in[2];
    const int*   dst  = (const int*)d_in[3];
    float* out = (float*)d_out;

    int n_nodes = in_sizes[0] / D_FEAT;
    int n_edges = in_sizes[2];
    int nb = (n_nodes + BUCKET_NODES - 1) / BUCKET_NODES;
    int nchunk = (n_edges + CHUNK_E - 1) / CHUNK_E;

    // bucket-sort path ws (4B elems):
    // nfb[N*32 bf16] | inv_norm[N] | bucket_base[nb+1] | total[MAX_NB]
    //   | chunk_hist[nb*nchunk] | recs[E]
    size_t nfb_bytes = (size_t)n_nodes * D_FEAT * 2;
    size_t need_sort = nfb_bytes +
                       ((size_t)n_nodes + (nb + 1) + MAX_NB +
                        (size_t)nb * nchunk + (size_t)n_edges) * 4;
    size_t need_ll = nfb_bytes + (size_t)n_nodes * 8 + (size_t)n_edges * 8;

    bool sort_ok = (ws_size >= need_sort) && (nb <= MAX_NB) &&
                   (n_nodes <= (1 << 24));

    if (sort_ok) {
        unsigned short* nfb = (unsigned short*)d_ws;
        float* inv_norm   = (float*)((char*)d_ws + nfb_bytes);
        int* bucket_base  = (int*)(inv_norm + n_nodes);
        int* total        = bucket_base + (nb + 1);
        int* chunk_hist   = total + MAX_NB;
        int* recs         = chunk_hist + (size_t)nb * nchunk;

        {
            int tt = n_nodes * 8;
            prep_kernel<<<(tt + 255) / 256, 256, 0, stream>>>(feat, nfb, inv_norm, n_nodes);
        }
        hist_kernel<<<nchunk, 256, 0, stream>>>(dst, chunk_hist, n_edges, nb, nchunk);
        {
            int blocks = (nb + 3) / 4;   // 4 waves per 256-thr block
            col_prefix_kernel<<<blocks, 256, 0, stream>>>(chunk_hist, total, nchunk, nb);
        }
        base_scan_kernel<<<1, 256, 0, stream>>>(total, bucket_base, nb, n_edges);
        scatter_kernel<<<nchunk, 256, 0, stream>>>(src, dst, chunk_hist, bucket_base,
                                                   recs, n_edges, nb, nchunk);
        bucket_aggregate_kernel<<<nb, 256, 0, stream>>>(
            nfb, inv_norm, bucket_base, recs, beta, out, n_nodes);
    } else if (ws_size >= need_ll) {
        unsigned short* nfb = (unsigned short*)d_ws;
        float* inv_norm = (float*)((char*)d_ws + nfb_bytes);
        int*   head     = (int*)(inv_norm + n_nodes);
        int2*  rec      = (int2*)(head + n_nodes);

        hipMemsetAsync(head, 0xFF, (size_t)n_nodes * sizeof(int), stream);
        {
            int tt = n_nodes * 8;
            prep_kernel<<<(tt + 255) / 256, 256, 0, stream>>>(feat, nfb, inv_norm, n_nodes);
        }
        link_packed_kernel<<<2048, 256, 0, stream>>>(src, dst, head, rec, n_edges);
        {
            int tt = n_nodes * 4;
            fused_chase_bf16_kernel<<<(tt + 255) / 256, 256, 0, stream>>>(
                nfb, inv_norm, head, rec, beta, out, n_nodes);
        }
    } else {
        float* inv_norm = (float*)d_ws;
        float* s_sum    = inv_norm + n_nodes;
        float* p        = s_sum + n_nodes;

        hipMemsetAsync(s_sum, 0, (size_t)n_nodes * sizeof(float), stream);
        hipMemsetAsync(out, 0, (size_t)out_size * sizeof(float), stream);

        {
            int tt = n_nodes * 8;
            node_invnorm_kernel<<<(tt + 255) / 256, 256, 0, stream>>>(feat, inv_norm, n_nodes);
        }
        {
            long long tt = (long long)n_edges * 8;
            edge_p_kernel<<<(int)((tt + 255) / 256), 256, 0, stream>>>(
                feat, inv_norm, src, dst, beta, p, s_sum, n_edges);
        }
        {
            long long tt = (long long)n_edges * 32;
            aggregate_atomic_kernel<<<(int)((tt + 255) / 256), 256, 0, stream>>>(
                feat, src, dst, p, s_sum, out, n_edges);
        }
    }
}